// Round 1
// baseline (2605.514 us; speedup 1.0000x reference)
//
#include <hip/hip_runtime.h>
#include <math.h>

// Monotone encoding of float into unsigned so atomicMax works for all signs.
__device__ __forceinline__ unsigned encodef(float f) {
    unsigned u = __float_as_uint(f);
    return (u & 0x80000000u) ? ~u : (u | 0x80000000u);
}
__device__ __forceinline__ float decodef(unsigned u) {
    return (u & 0x80000000u) ? __uint_as_float(u & 0x7FFFFFFFu)
                             : __uint_as_float(~u);
}

// K0: init per-segment max/sum scratch (ws is poisoned 0xAA every call).
__global__ void k_init(unsigned* __restrict__ segmax, float* __restrict__ segsum, int B) {
    int i = blockIdx.x * blockDim.x + threadIdx.x;
    if (i < B) { segmax[i] = 0u; segsum[i] = 0.0f; }
}

// K1: gate[n] = feat[n,:] . w + b ; atomicMax per segment.
// One 64-lane wave handles 2 rows: lanes 0-31 row n0, lanes 32-63 row n0+1.
// Each lane loads float4 (16B) -> 1KB contiguous per wave per load.
__global__ __launch_bounds__(256) void k_gate(
        const float* __restrict__ feat, const float* __restrict__ w,
        const float* __restrict__ bptr, const int* __restrict__ seg,
        float* __restrict__ gate, unsigned* __restrict__ segmax, int N) {
    int gtid = blockIdx.x * blockDim.x + threadIdx.x;
    int wave = gtid >> 6;
    int lane = threadIdx.x & 63;
    int half = lane >> 5;   // which of the 2 rows
    int l32  = lane & 31;
    int n = wave * 2 + half;
    if (n >= N) return;
    const float4 f4 = ((const float4*)(feat + (size_t)n * 128))[l32];
    const float4 w4 = ((const float4*)w)[l32];
    float v = f4.x * w4.x + f4.y * w4.y + f4.z * w4.z + f4.w * w4.w;
    // reduce within each 32-lane half (xor masks < 32 stay inside the half)
    v += __shfl_xor(v, 1);
    v += __shfl_xor(v, 2);
    v += __shfl_xor(v, 4);
    v += __shfl_xor(v, 8);
    v += __shfl_xor(v, 16);
    if (l32 == 0) {
        v += bptr[0];
        gate[n] = v;
        atomicMax(&segmax[seg[n]], encodef(v));
    }
}

// K2: e = exp(gate - segmax); per-segment sum with run-local accumulation
// (sorted segment_ids -> ~1 atomic per thread). Also writes segment start
// offsets: segstart[b] = first n with seg[n] >= b; segstart[B] = N.
__global__ __launch_bounds__(256) void k_expsum(
        const float* __restrict__ gate, const int* __restrict__ seg,
        const unsigned* __restrict__ segmax, float* __restrict__ segsum,
        int* __restrict__ segstart, int N, int B) {
    long base = (long)(blockIdx.x * blockDim.x + threadIdx.x) * 8;
    if (base >= N) return;
    int cnt = (int)((N - base < 8) ? (N - base) : 8);
    int prev = (base == 0) ? -1 : seg[base - 1];
    float acc = 0.0f;
    int accseg = -1;
    for (int i = 0; i < cnt; ++i) {
        long n = base + i;
        int s = seg[n];
        if (s != prev) {
            for (int bb = prev + 1; bb <= s; ++bb) segstart[bb] = (int)n;
            prev = s;
        }
        float e = expf(gate[n] - decodef(segmax[s]));
        if (s == accseg) {
            acc += e;
        } else {
            if (accseg >= 0) atomicAdd(&segsum[accseg], acc);
            acc = e; accseg = s;
        }
    }
    if (accseg >= 0) atomicAdd(&segsum[accseg], acc);
    if (base + cnt == (long)N) {
        for (int bb = prev + 1; bb <= B; ++bb) segstart[bb] = N;
    }
}

// K3: one block per segment. 256 threads = 8 row-groups x 32 lanes.
// Lane cl covers columns [4*cl, 4*cl+4). alpha recomputed from gate.
__global__ __launch_bounds__(256) void k_readout(
        const float* __restrict__ feat, const float* __restrict__ gate,
        const int* __restrict__ segstart, const unsigned* __restrict__ segmax,
        const float* __restrict__ segsum, float* __restrict__ readout,
        float* __restrict__ alpha, int B) {
    int b = blockIdx.x;
    int start = segstart[b], end = segstart[b + 1];
    float m = decodef(segmax[b]);
    float inv = (end > start) ? 1.0f / segsum[b] : 0.0f;
    int t  = threadIdx.x;
    int rg = t >> 5;      // row group 0..7
    int cl = t & 31;      // column lane
    float4 acc = make_float4(0.f, 0.f, 0.f, 0.f);
    for (int n = start + rg; n < end; n += 8) {
        float a = expf(gate[n] - m) * inv;       // broadcast load of gate[n]
        float4 f = ((const float4*)(feat + (size_t)n * 128))[cl];
        acc.x += f.x * a; acc.y += f.y * a; acc.z += f.z * a; acc.w += f.w * a;
        if (cl == 0) alpha[n] = a;
    }
    __shared__ float4 red[256];
    red[t] = acc;
    __syncthreads();
    #pragma unroll
    for (int off = 4; off >= 1; off >>= 1) {
        if (rg < off) {
            float4 o = red[t + off * 32];
            red[t].x += o.x; red[t].y += o.y; red[t].z += o.z; red[t].w += o.w;
        }
        __syncthreads();
    }
    if (rg == 0) ((float4*)(readout + (size_t)b * 128))[cl] = red[t];
}

extern "C" void kernel_launch(void* const* d_in, const int* in_sizes, int n_in,
                              void* d_out, int out_size, void* d_ws, size_t ws_size,
                              hipStream_t stream) {
    const float* feat  = (const float*)d_in[0];
    const float* wgate = (const float*)d_in[1];
    const float* bgate = (const float*)d_in[2];
    const int*   seg   = (const int*)d_in[3];

    const int N = in_sizes[3];              // 1,000,000 nodes
    const int D = in_sizes[1];              // 128 (w_gate is [D,1])
    const int B = (out_size - N) / D;       // 1024 graphs
    (void)D;

    float* readout = (float*)d_out;                    // [B,128]
    float* alpha   = (float*)d_out + (size_t)B * 128;  // [N]

    char* ws = (char*)d_ws;
    float*    gate     = (float*)ws;                                  // N floats
    unsigned* segmax   = (unsigned*)(ws + (size_t)N * 4);             // B uints
    float*    segsum   = (float*)(ws + (size_t)N * 4 + (size_t)B * 4);// B floats
    int*      segstart = (int*)(ws + (size_t)N * 4 + (size_t)B * 8);  // B+1 ints

    k_init<<<(B + 255) / 256, 256, 0, stream>>>(segmax, segsum, B);

    // 2 rows per wave, 4 waves per 256-thread block -> 8 rows per block
    int blocks1 = (N + 7) / 8;
    k_gate<<<blocks1, 256, 0, stream>>>(feat, wgate, bgate, seg, gate, segmax, N);

    int threads2 = (N + 7) / 8;
    k_expsum<<<(threads2 + 255) / 256, 256, 0, stream>>>(gate, seg, segmax, segsum,
                                                         segstart, N, B);

    k_readout<<<B, 256, 0, stream>>>(feat, gate, segstart, segmax, segsum,
                                     readout, alpha, B);
}

// Round 2
// 790.957 us; speedup vs baseline: 3.2941x; 3.2941x over previous
//
#include <hip/hip_runtime.h>
#include <math.h>

// K0: segment start offsets from sorted segment ids.
// segstart[b] = first n with seg[n] >= b ; segstart[B] = N. Covers empty segs.
__global__ __launch_bounds__(256) void k_segstart(
        const int* __restrict__ seg, int* __restrict__ segstart, int N, int B) {
    int i = blockIdx.x * blockDim.x + threadIdx.x;
    if (i >= N) return;
    int s = seg[i];
    int p = (i == 0) ? -1 : seg[i - 1];
    for (int bb = p + 1; bb <= s; ++bb) segstart[bb] = i;
    if (i == N - 1)
        for (int bb = s + 1; bb <= B; ++bb) segstart[bb] = N;
}

// Dot of one feat row (32 lanes x float4) with w; butterfly leaves the full
// sum in ALL 32 lanes of the half-wave (xor masks < 32 stay inside the half).
__device__ __forceinline__ float rowdot(float4 f, float4 w4) {
    float v = f.x * w4.x + f.y * w4.y + f.z * w4.z + f.w * w4.w;
    v += __shfl_xor(v, 1);
    v += __shfl_xor(v, 2);
    v += __shfl_xor(v, 4);
    v += __shfl_xor(v, 8);
    v += __shfl_xor(v, 16);
    return v;
}

// K1: one block per segment. 256 threads = 8 row-groups x 32 column-lanes.
// Pass 1: online softmax (running max m, rescaled sum s) per row-group,
//         combined across groups in LDS. No gate storage, no atomics.
// Pass 2: re-stream feat, recompute gate, write alpha, accumulate readout.
__global__ __launch_bounds__(256) void k_pool(
        const float* __restrict__ feat, const float* __restrict__ w,
        const float* __restrict__ bptr, const int* __restrict__ segstart,
        float* __restrict__ readout, float* __restrict__ alpha, int B) {
    int b = blockIdx.x;
    int start = segstart[b], end = segstart[b + 1];
    int t = threadIdx.x, rg = t >> 5, cl = t & 31;

    const float4 w4 = ((const float4*)w)[cl];
    const float bias = bptr[0];
    const float4* featv = (const float4*)feat;

    // ---- pass 1: per-group online (m, s) ----
    float m = -INFINITY, s = 0.0f;
    int n0 = start + rg;
    float4 f = (n0 < end) ? featv[(size_t)n0 * 32 + cl] : make_float4(0, 0, 0, 0);
    for (int n = n0; n < end; n += 8) {
        float4 fn = (n + 8 < end) ? featv[(size_t)(n + 8) * 32 + cl]
                                  : make_float4(0, 0, 0, 0);
        float g = rowdot(f, w4) + bias;
        if (g > m) { s = s * __expf(m - g) + 1.0f; m = g; }
        else       { s += __expf(g - m); }
        f = fn;
    }

    __shared__ float mred[8], sred[8];
    if (cl == 0) { mred[rg] = m; sred[rg] = s; }
    __syncthreads();
    float M = -INFINITY;
    #pragma unroll
    for (int g2 = 0; g2 < 8; ++g2) M = fmaxf(M, mred[g2]);
    float S = 0.0f;
    #pragma unroll
    for (int g2 = 0; g2 < 8; ++g2)
        if (sred[g2] > 0.0f) S += sred[g2] * __expf(mred[g2] - M);
    const float inv = (S > 0.0f) ? 1.0f / S : 0.0f;

    // ---- pass 2: alpha + weighted readout ----
    float4 acc = make_float4(0, 0, 0, 0);
    f = (n0 < end) ? featv[(size_t)n0 * 32 + cl] : make_float4(0, 0, 0, 0);
    for (int n = n0; n < end; n += 8) {
        float4 fn = (n + 8 < end) ? featv[(size_t)(n + 8) * 32 + cl]
                                  : make_float4(0, 0, 0, 0);
        float g = rowdot(f, w4) + bias;
        float a = __expf(g - M) * inv;
        acc.x += f.x * a; acc.y += f.y * a; acc.z += f.z * a; acc.w += f.w * a;
        if (cl == 0) alpha[n] = a;
        f = fn;
    }

    __shared__ float4 red[256];
    red[t] = acc;
    __syncthreads();
    #pragma unroll
    for (int off = 4; off >= 1; off >>= 1) {
        if (rg < off) {
            float4 o = red[t + off * 32];
            red[t].x += o.x; red[t].y += o.y; red[t].z += o.z; red[t].w += o.w;
        }
        __syncthreads();
    }
    if (rg == 0) ((float4*)(readout + (size_t)b * 128))[cl] = red[t];
}

extern "C" void kernel_launch(void* const* d_in, const int* in_sizes, int n_in,
                              void* d_out, int out_size, void* d_ws, size_t ws_size,
                              hipStream_t stream) {
    const float* feat  = (const float*)d_in[0];
    const float* wgate = (const float*)d_in[1];
    const float* bgate = (const float*)d_in[2];
    const int*   seg   = (const int*)d_in[3];

    const int N = in_sizes[3];              // 1,000,000 nodes
    const int D = in_sizes[1];              // 128
    const int B = (out_size - N) / D;       // 1024 graphs

    float* readout = (float*)d_out;                    // [B,128]
    float* alpha   = (float*)d_out + (size_t)B * 128;  // [N]

    int* segstart = (int*)d_ws;                        // B+1 ints

    k_segstart<<<(N + 255) / 256, 256, 0, stream>>>(seg, segstart, N, B);
    k_pool<<<B, 256, 0, stream>>>(feat, wgate, bgate, segstart,
                                  readout, alpha, B);
}